// Round 1
// baseline (1509.139 us; speedup 1.0000x reference)
//
#include <hip/hip_runtime.h>

// LSTM: B=4096, T=336, I=21, H=50, OUT=24. All fp32.
// One 256-thread workgroup owns WB=8 batch elements for the full sequence.
// Grid = 512 workgroups -> 2 wg/CU (LDS 78.2KB/wg), 2 waves/SIMD.

#define T_SEQ 336
#define I_IN  21
#define HID   50
#define O_OUT 24
#define WB    8
#define NT    256
#define NG    200          // 4*HID gate rows (i,f,g,o stacked)
#define IH_PAD 24          // W_ih row pad (16B-aligned, pads zeroed)
#define HH_PAD 52          // W_hh / h row pad
#define X_PAD  28          // x row pad
#define G_PAD  201         // gate buffer row pad (odd -> conflict-free writes)

__device__ __forceinline__ float frcp(float v) { return __builtin_amdgcn_rcpf(v); }
__device__ __forceinline__ float sigm(float v) { return frcp(1.f + __expf(-v)); }
__device__ __forceinline__ float tanh_f(float v) {
    float av = __builtin_fabsf(v);
    float e  = __expf(-2.f * av);
    float t  = (1.f - e) * frcp(1.f + e);
    return __builtin_copysignf(t, v);
}

__global__ __launch_bounds__(NT, 2)
void lstm_fused(const float* __restrict__ x,
                const float* __restrict__ W_ih,
                const float* __restrict__ W_hh,
                const float* __restrict__ b_ih,
                const float* __restrict__ b_hh,
                const float* __restrict__ W_fc,
                const float* __restrict__ b_fc,
                float* __restrict__ out)
{
    __shared__ float sWih[NG * IH_PAD];
    __shared__ float sWhh[NG * HH_PAD];
    __shared__ float sBias[NG];
    __shared__ float sWfc[O_OUT * HH_PAD];
    __shared__ float sBfc[O_OUT];
    __shared__ float sX[2][WB * X_PAD];
    __shared__ float sH[2][WB * HH_PAD];
    __shared__ float sG[WB * G_PAD];

    const int tid = threadIdx.x;
    const int b0  = blockIdx.x * WB;

    // ---- zero-init LDS (pads MUST be 0.0f; LDS is uninitialized garbage) ----
    for (int i = tid; i < NG * IH_PAD;    i += NT) sWih[i] = 0.f;
    for (int i = tid; i < NG * HH_PAD;    i += NT) sWhh[i] = 0.f;
    for (int i = tid; i < O_OUT * HH_PAD; i += NT) sWfc[i] = 0.f;
    for (int i = tid; i < 2 * WB * X_PAD;  i += NT) (&sX[0][0])[i] = 0.f;
    for (int i = tid; i < 2 * WB * HH_PAD; i += NT) (&sH[0][0])[i] = 0.f;
    __syncthreads();

    // ---- stage weights into LDS (once; amortized over 336 steps) ----
    for (int i = tid; i < NG * I_IN; i += NT)
        sWih[(i / I_IN) * IH_PAD + (i % I_IN)] = W_ih[i];
    for (int i = tid; i < NG * HID; i += NT)
        sWhh[(i / HID) * HH_PAD + (i % HID)] = W_hh[i];
    for (int i = tid; i < O_OUT * HID; i += NT)
        sWfc[(i / HID) * HH_PAD + (i % HID)] = W_fc[i];
    if (tid < NG)    sBias[tid] = b_ih[tid] + b_hh[tid];
    if (tid < O_OUT) sBfc[tid]  = b_fc[tid];

    // ---- roles ----
    // Gate phase: lane = batch (tid&7), chunk = gate-row group (tid>>3, 0..31).
    // 200 rows = 24 chunks x 6 + 8 chunks x 7; chunks 24..31 live in wave 3,
    // so every wave has a uniform row count (no divergence waste).
    const int b_l   = tid & (WB - 1);
    const int chunk = tid >> 3;
    const int rbase = (chunk < 24) ? 6 * chunk : 144 + 7 * (chunk - 24);
    const int rcnt  = (chunk < 24) ? 6 : 7;

    // x staging role: WB*21 = 168 words per step, one per thread (tid<168)
    const bool stg = tid < WB * I_IN;
    const int  sb  = tid / I_IN;
    const int  sk  = tid % I_IN;
    const float* xg = x + (size_t)(b0 + sb) * T_SEQ * I_IN + sk;

    // update role: 400 (b,u) tasks; thread owns tid and tid+256 (c in regs)
    const int  p2   = tid + NT;
    const bool has2 = p2 < WB * HID;
    const int  ub1 = tid / HID, uu1 = tid % HID;
    const int  ub2 = p2 / HID,  uu2 = p2 % HID;
    float c1 = 0.f, c2 = 0.f;

    // stage x(t=0)
    if (stg) sX[0][sb * X_PAD + sk] = xg[0];

    for (int t = 0; t < T_SEQ; ++t) {
        const int cur = t & 1, nxt = cur ^ 1;

        // prefetch x(t+1) from global; latency hides under gate compute
        float pf = 0.f;
        const bool do_pf = stg && (t + 1 < T_SEQ);
        if (do_pf) pf = xg[(size_t)(t + 1) * I_IN];

        __syncthreads();   // B1: sX[cur] staged, sH[cur] written by iter t-1

        // cache this batch element's x and h in registers (ds_read_b128)
        float4 xr[6], hr[13];
        {
            const float4* xs = (const float4*)&sX[cur][b_l * X_PAD];
            #pragma unroll
            for (int i = 0; i < 6; ++i) xr[i] = xs[i];
            const float4* hs = (const float4*)&sH[cur][b_l * HH_PAD];
            #pragma unroll
            for (int i = 0; i < 13; ++i) hr[i] = hs[i];
        }

        // ---- gate pre-activations: rcnt rows of 76 padded MACs ----
        for (int r = 0; r < rcnt; ++r) {
            const int row = rbase + r;
            const float4* wi = (const float4*)&sWih[row * IH_PAD];
            const float4* wh = (const float4*)&sWhh[row * HH_PAD];
            float a0 = sBias[row], a1 = 0.f, a2 = 0.f, a3 = 0.f;
            #pragma unroll
            for (int i = 0; i < 6; ++i) {
                const float4 w = wi[i], v = xr[i];
                a0 = __builtin_fmaf(w.x, v.x, a0);
                a1 = __builtin_fmaf(w.y, v.y, a1);
                a2 = __builtin_fmaf(w.z, v.z, a2);
                a3 = __builtin_fmaf(w.w, v.w, a3);
            }
            #pragma unroll
            for (int i = 0; i < 13; ++i) {
                const float4 w = wh[i], v = hr[i];
                a0 = __builtin_fmaf(w.x, v.x, a0);
                a1 = __builtin_fmaf(w.y, v.y, a1);
                a2 = __builtin_fmaf(w.z, v.z, a2);
                a3 = __builtin_fmaf(w.w, v.w, a3);
            }
            sG[b_l * G_PAD + row] = (a0 + a1) + (a2 + a3);
        }

        __syncthreads();   // B2: all 200 gate rows ready

        // ---- pointwise LSTM cell update; h(t) -> sH[nxt] ----
        {
            const float gi = sG[ub1 * G_PAD + uu1];
            const float gf = sG[ub1 * G_PAD + HID + uu1];
            const float gc = sG[ub1 * G_PAD + 2 * HID + uu1];
            const float go = sG[ub1 * G_PAD + 3 * HID + uu1];
            c1 = sigm(gf) * c1 + sigm(gi) * tanh_f(gc);
            sH[nxt][ub1 * HH_PAD + uu1] = sigm(go) * tanh_f(c1);
        }
        if (has2) {
            const float gi = sG[ub2 * G_PAD + uu2];
            const float gf = sG[ub2 * G_PAD + HID + uu2];
            const float gc = sG[ub2 * G_PAD + 2 * HID + uu2];
            const float go = sG[ub2 * G_PAD + 3 * HID + uu2];
            c2 = sigm(gf) * c2 + sigm(gi) * tanh_f(gc);
            sH[nxt][ub2 * HH_PAD + uu2] = sigm(go) * tanh_f(c2);
        }

        // commit prefetched x(t+1) into the other buffer (post-B2: safe)
        if (do_pf) sX[nxt][sb * X_PAD + sk] = pf;
    }

    __syncthreads();
    // final h is in sH[(T_SEQ-1+1)&1] == sH[0] (T_SEQ even)
    // FC head: WB*24 = 192 outputs
    if (tid < WB * O_OUT) {
        const int fb = tid / O_OUT, fo = tid % O_OUT;
        const float4* hh = (const float4*)&sH[0][fb * HH_PAD];
        const float4* wf = (const float4*)&sWfc[fo * HH_PAD];
        float a0 = sBfc[fo], a1 = 0.f, a2 = 0.f, a3 = 0.f;
        #pragma unroll
        for (int i = 0; i < 13; ++i) {
            const float4 h = hh[i], w = wf[i];
            a0 = __builtin_fmaf(w.x, h.x, a0);
            a1 = __builtin_fmaf(w.y, h.y, a1);
            a2 = __builtin_fmaf(w.z, h.z, a2);
            a3 = __builtin_fmaf(w.w, h.w, a3);
        }
        out[(size_t)(b0 + fb) * O_OUT + fo] = (a0 + a1) + (a2 + a3);
    }
}

extern "C" void kernel_launch(void* const* d_in, const int* in_sizes, int n_in,
                              void* d_out, int out_size, void* d_ws, size_t ws_size,
                              hipStream_t stream)
{
    const float* x    = (const float*)d_in[0];
    const float* W_ih = (const float*)d_in[1];
    const float* W_hh = (const float*)d_in[2];
    const float* b_ih = (const float*)d_in[3];
    const float* b_hh = (const float*)d_in[4];
    const float* W_fc = (const float*)d_in[5];
    const float* b_fc = (const float*)d_in[6];
    float* out = (float*)d_out;

    const int n_wg = 4096 / WB;   // 512
    lstm_fused<<<dim3(n_wg), dim3(NT), 0, stream>>>(
        x, W_ih, W_hh, b_ih, b_hh, W_fc, b_fc, out);
}

// Round 2
// 492.231 us; speedup vs baseline: 3.0659x; 3.0659x over previous
//
#include <hip/hip_runtime.h>

// LSTM B=4096 T=336 I=21 H=50 OUT=24, fp32 in/out.
// MFMA bf16 2-limb (Markidis) version. 256 wgs x 256 thr, MB=16 batch/wg.
// gates[m=batch 16][n=packed row 256] = act[m][k 96] . W'[n][k], 3 K-chunks of 32:
//   kc0,kc1 = h (cols>=50 zero-padded), kc2 = x (cols>=21 zero-padded)
// Packed row n = unit*4 + gate  (gate order i,f,g,o), units 0..63 (>=50 pad).
// Wave w owns N-tiles 4w..4w+3; B limb fragments live in VGPRs (built once).

#define T_SEQ 336
#define I_IN  21
#define HID   50
#define O_OUT 24
#define MB    16
#define NT    256

typedef short bf16x8 __attribute__((ext_vector_type(8)));
typedef float f32x4  __attribute__((ext_vector_type(4)));

// hbuf row (per batch): 64 k-slots as 8 blocks of [8 hi][8 lo] shorts = 128 + 8 pad = 136
#define HROW 136
// xbuf row: 32 k-slots: 4 blocks of [8hi][8lo] = 64 + 8 pad = 72
#define XROW 72
// sG2: row n (0..207) of 16 batch cols + 4 pad = 20 floats (transposed gate buffer)
#define GROW 20

static __device__ __forceinline__ unsigned short f2bf(float f) {
    unsigned u = __builtin_bit_cast(unsigned, f);
    return (unsigned short)((u + 0x7FFFu + ((u >> 16) & 1u)) >> 16);
}
static __device__ __forceinline__ float bf2f(unsigned short s) {
    unsigned u = ((unsigned)s) << 16;
    return __builtin_bit_cast(float, u);
}
static __device__ __forceinline__ float frcp(float v) { return __builtin_amdgcn_rcpf(v); }
static __device__ __forceinline__ float sigm(float v) { return frcp(1.f + __expf(-v)); }
static __device__ __forceinline__ float tanh_f(float v) {
    float av = __builtin_fabsf(v);
    float e  = __expf(-2.f * av);
    float t  = (1.f - e) * frcp(1.f + e);
    return __builtin_copysignf(t, v);
}

__global__ __launch_bounds__(NT, 1)
void lstm_mfma(const float* __restrict__ x,
               const float* __restrict__ W_ih,
               const float* __restrict__ W_hh,
               const float* __restrict__ b_ih,
               const float* __restrict__ b_hh,
               const float* __restrict__ W_fc,
               const float* __restrict__ b_fc,
               float* __restrict__ out)
{
    __shared__ short hbuf[MB * HROW];
    __shared__ short xbuf[2][MB * XROW];
    __shared__ float sG2[208 * GROW];

    const int tid  = threadIdx.x;
    const int lane = tid & 63;
    const int wv   = tid >> 6;
    const int nl   = lane & 15;   // A: m (batch) / B: n_local
    const int q    = lane >> 4;   // quad
    const int b0   = blockIdx.x * MB;

    // ---- zero h/x buffers (pads must stay 0 forever) ----
    for (int i = tid; i < MB * HROW; i += NT) hbuf[i] = 0;
    for (int i = tid; i < 2 * MB * XROW; i += NT) (&xbuf[0][0])[i] = 0;

    // ---- build B limb fragments in VGPRs (once) ----
    // B[k][n]: lane holds n = tile*16 + nl, k = kc*32 + q*8 + j
    bf16x8 Bh[4][3], Bl[4][3];
    float biasn[4];
    #pragma unroll
    for (int nt = 0; nt < 4; ++nt) {
        const int gtile = wv * 4 + nt;
        const int n  = gtile * 16 + nl;
        const int u  = n >> 2, gt = n & 3;
        const bool vrow = (u < HID);
        const int orig = gt * HID + u;           // original gate-row (i,f,g,o blocks)
        biasn[nt] = vrow ? (b_ih[orig] + b_hh[orig]) : 0.f;
        #pragma unroll
        for (int kc = 0; kc < 3; ++kc) {
            #pragma unroll
            for (int j = 0; j < 8; ++j) {
                const int k = kc * 32 + q * 8 + j;
                float wval = 0.f;
                if (kc < 2) { if (vrow && k < HID) wval = W_hh[orig * HID + k]; }
                else { const int ki = k - 64; if (vrow && ki < I_IN) wval = W_ih[orig * I_IN + ki]; }
                const unsigned short hi = f2bf(wval);
                const float lo = wval - bf2f(hi);
                Bh[nt][kc][j] = (short)hi;
                Bl[nt][kc][j] = (short)f2bf(lo);
            }
        }
    }

    __syncthreads();   // zero-init done before staging x(0)

    // ---- stage x(t=0) limbs ----
    if (tid < 168) {
        #pragma unroll
        for (int s = 0; s < 2; ++s) {
            const int p = tid + s * 168;
            const int b = p / I_IN, i = p % I_IN;
            const float v = x[((size_t)(b0 + b) * T_SEQ + 0) * I_IN + i];
            const unsigned short hi = f2bf(v);
            const unsigned short lo = f2bf(v - bf2f(hi));
            xbuf[0][b * XROW + (i >> 3) * 16 + (i & 7)]     = (short)hi;
            xbuf[0][b * XROW + (i >> 3) * 16 + 8 + (i & 7)] = (short)lo;
        }
    }

    // pointwise cell state in registers: thread<200 owns tasks (tid, tid+200),
    // task p: up=p>>4 (unit-pair), b=p&15; units 2up, 2up+1.
    float cc[2][2] = {{0.f, 0.f}, {0.f, 0.f}};

    for (int t = 0; t < T_SEQ; ++t) {
        const int cur = t & 1, nxt = cur ^ 1;

        __syncthreads();  // B1: h(t)/x(t) staged; sG2 from t-1 consumed

        // prefetch x(t+1) (consumed after B2)
        float pf0 = 0.f, pf1 = 0.f;
        const bool do_pf = (tid < 168) && (t + 1 < T_SEQ);
        if (do_pf) {
            const int bA = tid / I_IN, iA = tid % I_IN;
            pf0 = x[((size_t)(b0 + bA) * T_SEQ + (t + 1)) * I_IN + iA];
            const int p1 = tid + 168;
            const int bB = p1 / I_IN, iB = p1 % I_IN;
            pf1 = x[((size_t)(b0 + bB) * T_SEQ + (t + 1)) * I_IN + iB];
        }

        // A fragments: lane m=nl, k = kc*32 + q*8 + j
        bf16x8 Ah[3], Al[3];
        #pragma unroll
        for (int kc = 0; kc < 2; ++kc) {
            const short* base = &hbuf[nl * HROW + (kc * 4 + q) * 16];
            Ah[kc] = *(const bf16x8*)(base);
            Al[kc] = *(const bf16x8*)(base + 8);
        }
        {
            const short* base = &xbuf[cur][nl * XROW + q * 16];
            Ah[2] = *(const bf16x8*)(base);
            Al[2] = *(const bf16x8*)(base + 8);
        }

        f32x4 acc[4];
        #pragma unroll
        for (int nt = 0; nt < 4; ++nt) {
            f32x4 a; a[0] = biasn[nt]; a[1] = biasn[nt]; a[2] = biasn[nt]; a[3] = biasn[nt];
            acc[nt] = a;
        }
        #pragma unroll
        for (int kc = 0; kc < 3; ++kc) {
            #pragma unroll
            for (int nt = 0; nt < 4; ++nt)
                acc[nt] = __builtin_amdgcn_mfma_f32_16x16x32_bf16(Ah[kc], Bh[nt][kc], acc[nt], 0, 0, 0);
            #pragma unroll
            for (int nt = 0; nt < 4; ++nt)
                acc[nt] = __builtin_amdgcn_mfma_f32_16x16x32_bf16(Ah[kc], Bl[nt][kc], acc[nt], 0, 0, 0);
            #pragma unroll
            for (int nt = 0; nt < 4; ++nt)
                acc[nt] = __builtin_amdgcn_mfma_f32_16x16x32_bf16(Al[kc], Bh[nt][kc], acc[nt], 0, 0, 0);
        }

        // gates -> LDS, transposed: sG2[n][m]; C/D: n=lane&15, m=q*4+reg
        // regs are consecutive m -> one b128 store per tile.
        #pragma unroll
        for (int nt = 0; nt < 4; ++nt) {
            const int gtile = wv * 4 + nt;
            if (gtile < 13)   // tiles 13..15 are pure pad (units >= 52)
                *(f32x4*)&sG2[(gtile * 16 + nl) * GROW + q * 4] = acc[nt];
        }

        __syncthreads();  // B2: gates ready

        // ---- pointwise: c,h update ----
        if (tid < 200) {
            #pragma unroll
            for (int s = 0; s < 2; ++s) {
                const int p  = tid + s * 200;
                const int up = p >> 4, b = p & 15;
                const int r0 = up * 8;               // rows 8up..8up+7, col b
                #pragma unroll
                for (int uu = 0; uu < 2; ++uu) {
                    const float gi = sG2[(r0 + uu * 4 + 0) * GROW + b];
                    const float gf = sG2[(r0 + uu * 4 + 1) * GROW + b];
                    const float gg = sG2[(r0 + uu * 4 + 2) * GROW + b];
                    const float go = sG2[(r0 + uu * 4 + 3) * GROW + b];
                    float c = cc[s][uu];
                    c = sigm(gf) * c + sigm(gi) * tanh_f(gg);
                    cc[s][uu] = c;
                    const float h = sigm(go) * tanh_f(c);
                    const unsigned short hi = f2bf(h);
                    const unsigned short lo = f2bf(h - bf2f(hi));
                    const int u  = up * 2 + uu;
                    const int kb = u >> 3, kj = u & 7;
                    hbuf[b * HROW + kb * 16 + kj]     = (short)hi;
                    hbuf[b * HROW + kb * 16 + 8 + kj] = (short)lo;
                }
            }
        }

        // commit prefetched x(t+1) limbs
        if (do_pf) {
            {
                const int b = tid / I_IN, i = tid % I_IN;
                const unsigned short hi = f2bf(pf0);
                const unsigned short lo = f2bf(pf0 - bf2f(hi));
                xbuf[nxt][b * XROW + (i >> 3) * 16 + (i & 7)]     = (short)hi;
                xbuf[nxt][b * XROW + (i >> 3) * 16 + 8 + (i & 7)] = (short)lo;
            }
            {
                const int p1 = tid + 168;
                const int b = p1 / I_IN, i = p1 % I_IN;
                const unsigned short hi = f2bf(pf1);
                const unsigned short lo = f2bf(pf1 - bf2f(hi));
                xbuf[nxt][b * XROW + (i >> 3) * 16 + (i & 7)]     = (short)hi;
                xbuf[nxt][b * XROW + (i >> 3) * 16 + 8 + (i & 7)] = (short)lo;
            }
        }
    }

    __syncthreads();
    // ---- FC epilogue: out[b][o] = h . W_fc[o] + b_fc[o], 16x24 = 384 tasks ----
    if (tid < 192) {
        #pragma unroll
        for (int s = 0; s < 2; ++s) {
            const int idx = tid + s * 192;
            const int b = idx / O_OUT, o = idx % O_OUT;
            float a = b_fc[o];
            for (int u = 0; u < HID; ++u) {
                const int kb = u >> 3, kj = u & 7;
                const float hv = bf2f((unsigned short)hbuf[b * HROW + kb * 16 + kj])
                               + bf2f((unsigned short)hbuf[b * HROW + kb * 16 + 8 + kj]);
                a = __builtin_fmaf(hv, W_fc[o * HID + u], a);
            }
            out[(size_t)(b0 + b) * O_OUT + o] = a;
        }
    }
}

extern "C" void kernel_launch(void* const* d_in, const int* in_sizes, int n_in,
                              void* d_out, int out_size, void* d_ws, size_t ws_size,
                              hipStream_t stream)
{
    const float* x    = (const float*)d_in[0];
    const float* W_ih = (const float*)d_in[1];
    const float* W_hh = (const float*)d_in[2];
    const float* b_ih = (const float*)d_in[3];
    const float* b_hh = (const float*)d_in[4];
    const float* W_fc = (const float*)d_in[5];
    const float* b_fc = (const float*)d_in[6];
    float* out = (float*)d_out;

    lstm_mfma<<<dim3(4096 / MB), dim3(NT), 0, stream>>>(
        x, W_ih, W_hh, b_ih, b_hh, W_fc, b_fc, out);
}

// Round 3
// 437.728 us; speedup vs baseline: 3.4477x; 1.1245x over previous
//
#include <hip/hip_runtime.h>

// LSTM B=4096 T=336 I=21 H=50 OUT=24, fp32 in/out. MFMA bf16 2-limb.
// Round 3: D[m = packed gate row][n = batch]. A = weights (VGPR-resident),
// B = activations (LDS, bf16 limb pairs). Packed row = unit*4 + gate, so the
// C/D layout (col=lane&15=batch, row=q*4+reg) gives each lane the 4 gates of
// ONE unit in its 4 acc regs -> pointwise LSTM update entirely in registers.
// One barrier per step; h double-buffered. 256 wgs x 512 thr (8 waves/CU).

#define T_SEQ 336
#define I_IN  21
#define HID   50
#define O_OUT 24
#define MB    16
#define NT    512
#define NTILE 13        // 13 tiles x 16 rows = 208 packed rows (200 valid)

#define HROW 136        // shorts per batch: 8 blocks of [8 hi | 8 lo] + 8 pad
#define XROW 72         // 4 blocks of [8 hi | 8 lo] + 8 pad

typedef short bf16x8 __attribute__((ext_vector_type(8)));
typedef float f32x4  __attribute__((ext_vector_type(4)));

static __device__ __forceinline__ unsigned short f2bf(float f) {
    unsigned u = __builtin_bit_cast(unsigned, f);
    return (unsigned short)((u + 0x7FFFu + ((u >> 16) & 1u)) >> 16);
}
static __device__ __forceinline__ float bf2f(unsigned short s) {
    unsigned u = ((unsigned)s) << 16;
    return __builtin_bit_cast(float, u);
}
static __device__ __forceinline__ float frcp(float v) { return __builtin_amdgcn_rcpf(v); }
static __device__ __forceinline__ float sigm(float v) { return frcp(1.f + __expf(-v)); }
static __device__ __forceinline__ float tanh_f(float v) {
    float av = __builtin_fabsf(v);
    float e  = __expf(-2.f * av);
    float t  = (1.f - e) * frcp(1.f + e);
    return __builtin_copysignf(t, v);
}

__global__ __launch_bounds__(NT, 2)
void lstm_mfma3(const float* __restrict__ x,
                const float* __restrict__ W_ih,
                const float* __restrict__ W_hh,
                const float* __restrict__ b_ih,
                const float* __restrict__ b_hh,
                const float* __restrict__ W_fc,
                const float* __restrict__ b_fc,
                float* __restrict__ out)
{
    __shared__ short hbuf[2][MB * HROW];
    __shared__ short xbuf[2][MB * XROW];

    const int tid = threadIdx.x;
    const int lane = tid & 63;
    const int wv   = tid >> 6;     // 0..7
    const int nl   = lane & 15;    // B: batch col / A: row-in-tile
    const int q    = lane >> 4;    // quad
    const int b0   = blockIdx.x * MB;

    // ---- zero LDS (pads must stay 0 forever) ----
    for (int i = tid; i < 2 * MB * HROW; i += NT) (&hbuf[0][0])[i] = 0;
    for (int i = tid; i < 2 * MB * XROW; i += NT) (&xbuf[0][0])[i] = 0;

    // ---- wave -> M-tile assignment: waves 0..4 own {w, w+8}, 5..7 own {w} ----
    const int t1v  = wv + 8;
    const int ntl  = (t1v < NTILE) ? 2 : 1;
    const int tiles[2] = {wv, (t1v < NTILE) ? t1v : 0};

    // ---- A (weight) fragments + per-lane bias, built once ----
    // A[m=nl][k=kc*32+q*8+j]; packed row p = tile*16+nl -> unit=p>>2, gate=p&3
    bf16x8 Wh[2][3], Wl[2][3];
    f32x4  biasv[2];
    #pragma unroll
    for (int tt = 0; tt < 2; ++tt) {
        const int tile = tiles[tt];
        const int p    = tile * 16 + nl;
        const int unit = p >> 2, gate = p & 3;
        const bool vr  = (unit < HID);
        const int orig = gate * HID + unit;      // i,f,g,o stacked blocks
        // bias follows the D-row mapping: row q*4+r -> unit_b=tile*4+q, gate=r
        const int ub   = tile * 4 + q;
        #pragma unroll
        for (int r = 0; r < 4; ++r)
            biasv[tt][r] = (ub < HID) ? (b_ih[r * HID + ub] + b_hh[r * HID + ub]) : 0.f;
        #pragma unroll
        for (int kc = 0; kc < 3; ++kc) {
            #pragma unroll
            for (int j = 0; j < 8; ++j) {
                const int k = kc * 32 + q * 8 + j;
                float w = 0.f;
                if (vr) {
                    if (kc < 2) { if (k < HID) w = W_hh[orig * HID + k]; }
                    else { const int ki = k - 64; if (ki < I_IN) w = W_ih[orig * I_IN + ki]; }
                }
                const unsigned short hi = f2bf(w);
                const unsigned short lo = f2bf(w - bf2f(hi));
                Wh[tt][kc][j] = (short)hi;
                Wl[tt][kc][j] = (short)lo;
            }
        }
    }

    __syncthreads();   // zero-init visible before x(0)/h staging

    // ---- x staging role: 336 threads, one (b,i) each, persistent pointer ----
    const bool stg = tid < MB * I_IN;                  // 336
    const int  sb  = stg ? tid / I_IN : 0;
    const int  sk  = stg ? tid % I_IN : 0;
    const float* xg = x + (size_t)(b0 + sb) * T_SEQ * I_IN + sk;
    if (stg) {
        const float v = xg[0];
        const unsigned short hi = f2bf(v);
        const unsigned short lo = f2bf(v - bf2f(hi));
        xbuf[0][sb * XROW + (sk >> 3) * 16 + (sk & 7)]     = (short)hi;
        xbuf[0][sb * XROW + (sk >> 3) * 16 + 8 + (sk & 7)] = (short)lo;
    }

    // cell state: lane owns unit (tile*4+q) for batch nl, per owned tile
    float cst[2] = {0.f, 0.f};
    const int upt[2] = {tiles[0] * 4 + q, tiles[1] * 4 + q};

    for (int t = 0; t < T_SEQ; ++t) {
        const int cur = t & 1, nxt = cur ^ 1;

        // global prefetch x(t+1) (committed post-compute, used next iter)
        float pf = 0.f;
        const bool do_pf = stg && (t + 1 < T_SEQ);
        if (do_pf) pf = xg[(size_t)(t + 1) * I_IN];

        __syncthreads();   // hbuf[cur]/xbuf[cur] complete

        // ---- B (activation) fragments: B[k=q*8+j][n=nl] ----
        bf16x8 Bh[3], Bl[3];
        #pragma unroll
        for (int kc = 0; kc < 2; ++kc) {
            const short* base = &hbuf[cur][nl * HROW + (kc * 4 + q) * 16];
            Bh[kc] = *(const bf16x8*)(base);
            Bl[kc] = *(const bf16x8*)(base + 8);
        }
        {
            const short* base = &xbuf[cur][nl * XROW + q * 16];
            Bh[2] = *(const bf16x8*)(base);
            Bl[2] = *(const bf16x8*)(base + 8);
        }

        // ---- MFMA: acc[tt] = bias + W.act (3 limb products per kc) ----
        f32x4 acc[2];
        acc[0] = biasv[0];
        acc[1] = biasv[1];
        #pragma unroll
        for (int kc = 0; kc < 3; ++kc) {
            acc[0] = __builtin_amdgcn_mfma_f32_16x16x32_bf16(Wh[0][kc], Bh[kc], acc[0], 0, 0, 0);
            if (ntl == 2)
                acc[1] = __builtin_amdgcn_mfma_f32_16x16x32_bf16(Wh[1][kc], Bh[kc], acc[1], 0, 0, 0);
            acc[0] = __builtin_amdgcn_mfma_f32_16x16x32_bf16(Wh[0][kc], Bl[kc], acc[0], 0, 0, 0);
            if (ntl == 2)
                acc[1] = __builtin_amdgcn_mfma_f32_16x16x32_bf16(Wh[1][kc], Bl[kc], acc[1], 0, 0, 0);
            acc[0] = __builtin_amdgcn_mfma_f32_16x16x32_bf16(Wl[0][kc], Bh[kc], acc[0], 0, 0, 0);
            if (ntl == 2)
                acc[1] = __builtin_amdgcn_mfma_f32_16x16x32_bf16(Wl[1][kc], Bh[kc], acc[1], 0, 0, 0);
        }

        // ---- pointwise cell update, fully in registers ----
        #pragma unroll
        for (int tt = 0; tt < 2; ++tt) {
            if (tt < ntl) {
                const int u = upt[tt];
                if (u < HID) {
                    const float gi = acc[tt][0];
                    const float gf = acc[tt][1];
                    const float gg = acc[tt][2];
                    const float go = acc[tt][3];
                    float c = cst[tt];
                    c = sigm(gf) * c + sigm(gi) * tanh_f(gg);
                    cst[tt] = c;
                    const float h = sigm(go) * tanh_f(c);
                    const unsigned short hi = f2bf(h);
                    const unsigned short lo = f2bf(h - bf2f(hi));
                    hbuf[nxt][nl * HROW + (u >> 3) * 16 + (u & 7)]     = (short)hi;
                    hbuf[nxt][nl * HROW + (u >> 3) * 16 + 8 + (u & 7)] = (short)lo;
                }
            }
        }

        // commit prefetched x(t+1)
        if (do_pf) {
            const unsigned short hi = f2bf(pf);
            const unsigned short lo = f2bf(pf - bf2f(hi));
            xbuf[nxt][sb * XROW + (sk >> 3) * 16 + (sk & 7)]     = (short)hi;
            xbuf[nxt][sb * XROW + (sk >> 3) * 16 + 8 + (sk & 7)] = (short)lo;
        }
    }

    __syncthreads();
    // final h: t=335 wrote nxt=0
    // ---- FC epilogue: 16*24 = 384 tasks ----
    if (tid < MB * O_OUT) {
        const int b = tid / O_OUT, o = tid % O_OUT;
        float a = b_fc[o];
        for (int u = 0; u < HID; ++u) {
            const float hv = bf2f((unsigned short)hbuf[0][b * HROW + (u >> 3) * 16 + (u & 7)])
                           + bf2f((unsigned short)hbuf[0][b * HROW + (u >> 3) * 16 + 8 + (u & 7)]);
            a = __builtin_fmaf(hv, W_fc[o * HID + u], a);
        }
        out[(size_t)(b0 + b) * O_OUT + o] = a;
    }
}

extern "C" void kernel_launch(void* const* d_in, const int* in_sizes, int n_in,
                              void* d_out, int out_size, void* d_ws, size_t ws_size,
                              hipStream_t stream)
{
    const float* x    = (const float*)d_in[0];
    const float* W_ih = (const float*)d_in[1];
    const float* W_hh = (const float*)d_in[2];
    const float* b_ih = (const float*)d_in[3];
    const float* b_hh = (const float*)d_in[4];
    const float* W_fc = (const float*)d_in[5];
    const float* b_fc = (const float*)d_in[6];
    float* out = (float*)d_out;

    lstm_mfma3<<<dim3(4096 / MB), dim3(NT), 0, stream>>>(
        x, W_ih, W_hh, b_ih, b_hh, W_fc, b_fc, out);
}

// Round 4
// 372.730 us; speedup vs baseline: 4.0489x; 1.1744x over previous
//
#include <hip/hip_runtime.h>

// LSTM B=4096 T=336 I=21 H=50 OUT=24, fp32 in/out. MFMA bf16 2-limb.
// Round 4: 256 wgs x 832 thr = 13 waves, one 16-row M-tile per wave.
// D[m = packed gate row][n = batch16]; A = weights in VGPRs; B = activations
// in a unified conflict-free LDS buffer [buf][limb][kblock][batch][8]:
//   kblock 0..7  = h  (k 0..63, units 0..49 valid, rest zero-pad)
//   kblock 8..11 = x  (k 64..95, i = k-64 < 21 valid, rest zero-pad)
// Wave reads B frags at (const + lane*16B): contiguous, zero bank conflicts.
// Packed row = unit*4 + gate -> each lane's 4 acc regs are the 4 gates of one
// unit: pointwise LSTM update fully in registers. One barrier per step.

#define T_SEQ 336
#define I_IN  21
#define HID   50
#define O_OUT 24
#define MB    16
#define NT    832
#define NTILE 13
#define KB    12

#define AIDX(buf, limb, kb, n, j) (((((buf)*2 + (limb))*KB + (kb))*16 + (n))*8 + (j))

typedef short bf16x8 __attribute__((ext_vector_type(8)));
typedef float f32x4  __attribute__((ext_vector_type(4)));

// round-to-nearest bf16 (prologue / weights only)
static __device__ __forceinline__ unsigned short f2bf(float f) {
    unsigned u = __builtin_bit_cast(unsigned, f);
    return (unsigned short)((u + 0x7FFFu + ((u >> 16) & 1u)) >> 16);
}
static __device__ __forceinline__ float bf2f(unsigned short s) {
    unsigned u = ((unsigned)s) << 16;
    return __builtin_bit_cast(float, u);
}
// cheap truncation 2-limb split (per-step path): err ~2^-16 rel
static __device__ __forceinline__ void split2(float v, short& hi, short& lo) {
    const unsigned u = __builtin_bit_cast(unsigned, v);
    hi = (short)(u >> 16);
    const float hf = __builtin_bit_cast(float, u & 0xFFFF0000u);
    const float l  = v - hf;
    lo = (short)(__builtin_bit_cast(unsigned, l) >> 16);
}
static __device__ __forceinline__ float frcp(float v) { return __builtin_amdgcn_rcpf(v); }
static __device__ __forceinline__ float sigm(float v) { return frcp(1.f + __expf(-v)); }
static __device__ __forceinline__ float tanh_f(float v) {
    float av = __builtin_fabsf(v);
    float e  = __expf(-2.f * av);
    float t  = (1.f - e) * frcp(1.f + e);
    return __builtin_copysignf(t, v);
}

__global__ __launch_bounds__(NT)
void lstm_mfma4(const float* __restrict__ x,
                const float* __restrict__ W_ih,
                const float* __restrict__ W_hh,
                const float* __restrict__ b_ih,
                const float* __restrict__ b_hh,
                const float* __restrict__ W_fc,
                const float* __restrict__ b_fc,
                float* __restrict__ out)
{
    __shared__ short sAct[2 * 2 * KB * 16 * 8];   // 6144 shorts = 12 KB

    const int tid  = threadIdx.x;
    const int lane = tid & 63;
    const int wv   = tid >> 6;        // 0..12 == M-tile
    const int nl   = lane & 15;       // A: row-in-tile / B: batch col
    const int q    = lane >> 4;       // quad
    const int b0   = blockIdx.x * MB;

    // ---- zero-init (pads must stay 0 forever; h(0)=0) ----
    for (int i = tid; i < 2 * 2 * KB * 16 * 8; i += NT) sAct[i] = 0;

    // ---- A (weight) fragments + bias, built once ----
    // A[m=nl][k = kc*32 + q*8 + j]; packed row p = wv*16+nl -> unit=p>>2, gate=p&3
    bf16x8 Wh[3], Wl[3];
    f32x4  biasv;
    {
        const int p    = wv * 16 + nl;
        const int unit = p >> 2, gate = p & 3;
        const bool vr  = (unit < HID);
        const int orig = gate * HID + unit;       // i,f,g,o stacked row
        const int ub   = wv * 4 + q;              // unit for D rows q*4+r
        #pragma unroll
        for (int r = 0; r < 4; ++r)
            biasv[r] = (ub < HID) ? (b_ih[r * HID + ub] + b_hh[r * HID + ub]) : 0.f;
        #pragma unroll
        for (int kc = 0; kc < 3; ++kc) {
            #pragma unroll
            for (int j = 0; j < 8; ++j) {
                const int k = kc * 32 + q * 8 + j;
                float w = 0.f;
                if (vr) {
                    if (k < 64) { if (k < HID) w = W_hh[orig * HID + k]; }
                    else { const int ki = k - 64; if (ki < I_IN) w = W_ih[orig * I_IN + ki]; }
                }
                const unsigned short hi = f2bf(w);
                const unsigned short lo = f2bf(w - bf2f(hi));
                Wh[kc][j] = (short)hi;
                Wl[kc][j] = (short)lo;
            }
        }
    }

    __syncthreads();   // zero-init visible

    // ---- x staging role: threads 496..831 (waves 7..12), one (b,i) each ----
    const int  sid = tid - (NT - MB * I_IN);      // 0..335 for stg threads
    const bool stg = (sid >= 0);
    const int  sb  = stg ? sid / I_IN : 0;
    const int  sk  = stg ? sid % I_IN : 0;
    const float* xg = x + (size_t)(b0 + sb) * T_SEQ * I_IN + sk;
    if (stg) {
        short hi, lo;
        split2(xg[0], hi, lo);
        sAct[AIDX(0, 0, 8 + (sk >> 3), sb, sk & 7)] = hi;
        sAct[AIDX(0, 1, 8 + (sk >> 3), sb, sk & 7)] = lo;
    }

    // pointwise: lane owns unit uown for batch nl (c in register)
    const int  uown  = wv * 4 + q;
    const bool uval  = (uown < HID);
    float cst = 0.f;

    for (int t = 0; t < T_SEQ; ++t) {
        const int cur = t & 1, nxt = cur ^ 1;

        // prefetch x(t+1); committed post-compute into sAct[nxt]
        float pf = 0.f;
        const bool do_pf = stg && (t + 1 < T_SEQ);
        if (do_pf) pf = xg[(size_t)(t + 1) * I_IN];

        __syncthreads();   // sAct[cur] (h(t) + x(t)) complete

        // ---- MFMA: two accumulators, reads interleaved ----
        f32x4 aA = biasv;
        f32x4 aB = {0.f, 0.f, 0.f, 0.f};
        #pragma unroll
        for (int kc = 0; kc < 3; ++kc) {
            const int kb = kc * 4 + q;
            const bf16x8 Bh = *(const bf16x8*)&sAct[AIDX(cur, 0, kb, nl, 0)];
            const bf16x8 Bl = *(const bf16x8*)&sAct[AIDX(cur, 1, kb, nl, 0)];
            aA = __builtin_amdgcn_mfma_f32_16x16x32_bf16(Wh[kc], Bh, aA, 0, 0, 0);
            aB = __builtin_amdgcn_mfma_f32_16x16x32_bf16(Wh[kc], Bl, aB, 0, 0, 0);
            aA = __builtin_amdgcn_mfma_f32_16x16x32_bf16(Wl[kc], Bh, aA, 0, 0, 0);
        }

        // ---- pointwise cell update, in registers ----
        if (uval) {
            const float gi = aA[0] + aB[0];
            const float gf = aA[1] + aB[1];
            const float gg = aA[2] + aB[2];
            const float go = aA[3] + aB[3];
            float c = cst;
            c = sigm(gf) * c + sigm(gi) * tanh_f(gg);
            cst = c;
            const float h = sigm(go) * tanh_f(c);
            short hi, lo;
            split2(h, hi, lo);
            sAct[AIDX(nxt, 0, uown >> 3, nl, uown & 7)] = hi;
            sAct[AIDX(nxt, 1, uown >> 3, nl, uown & 7)] = lo;
        }

        // commit prefetched x(t+1)
        if (do_pf) {
            short hi, lo;
            split2(pf, hi, lo);
            sAct[AIDX(nxt, 0, 8 + (sk >> 3), sb, sk & 7)] = hi;
            sAct[AIDX(nxt, 1, 8 + (sk >> 3), sb, sk & 7)] = lo;
        }
    }

    __syncthreads();
    // final h: t=335 wrote buf 0
    // ---- FC epilogue: 16*24 = 384 tasks (one-time) ----
    if (tid < MB * O_OUT) {
        const int b = tid / O_OUT, o = tid % O_OUT;
        float a = b_fc[o];
        for (int u = 0; u < HID; ++u) {
            const float hv = bf2f((unsigned short)sAct[AIDX(0, 0, u >> 3, b, u & 7)])
                           + bf2f((unsigned short)sAct[AIDX(0, 1, u >> 3, b, u & 7)]);
            a = __builtin_fmaf(hv, W_fc[o * HID + u], a);
        }
        out[(size_t)(b0 + b) * O_OUT + o] = a;
    }
}

extern "C" void kernel_launch(void* const* d_in, const int* in_sizes, int n_in,
                              void* d_out, int out_size, void* d_ws, size_t ws_size,
                              hipStream_t stream)
{
    const float* x    = (const float*)d_in[0];
    const float* W_ih = (const float*)d_in[1];
    const float* W_hh = (const float*)d_in[2];
    const float* b_ih = (const float*)d_in[3];
    const float* b_hh = (const float*)d_in[4];
    const float* W_fc = (const float*)d_in[5];
    const float* b_fc = (const float*)d_in[6];
    float* out = (float*)d_out;

    lstm_mfma4<<<dim3(4096 / MB), dim3(NT), 0, stream>>>(
        x, W_ih, W_hh, b_ih, b_hh, W_fc, b_fc, out);
}